// Round 8
// baseline (316.695 us; speedup 1.0000x reference)
//
#include <hip/hip_runtime.h>
#include <hip/hip_bf16.h>
#include <math.h>

// ---------------------------------------------------------------------------
// FeatureNet (DGCNN edge-conv block), MI355X / gfx950, round 8.
//
// Round-8 change (kNN only; convs = round-7 MFMA versions):
//  * Pass A loads via float4 (1 ds_read_b128 vs 4 b32).
//  * Bound B' = max of 8 group minima (6 bpermutes vs 48); valid upper bound
//    on the 8th-smallest distance (8 distinct candidates <= B').
//  * Selection = ballot radix-select over 43-bit (dist,idx) keys: exact
//    lax.top_k SET (order within k irrelevant downstream), zero LDS ops.
// ---------------------------------------------------------------------------

#define B_   16
#define N_   2048
#define KNN  8
#define DIM  128
#define P_   (B_*N_*KNN)   // 262144
#define CAP  128
#define NBLK 2048          // conv blocks (128 p each)

typedef __attribute__((ext_vector_type(8))) short bf16x8;
typedef __attribute__((ext_vector_type(4))) float f32x4;

// ws layout (bytes)
#define OFF_G     0ull
#define SZ_G      ((size_t)3*P_*4)             // 3,145,728
#define OFF_Y2B   (OFF_G + SZ_G)
#define SZ_Y2B    ((size_t)DIM*P_*2)           // 67,108,864
#define OFF_WB2   (OFF_Y2B + SZ_Y2B)
#define SZ_WB     ((size_t)DIM*DIM*2)          // 32,768
#define OFF_WB3   (OFF_WB2 + SZ_WB)
#define OFF_STATS (OFF_WB3 + SZ_WB)
#define N_STATS   4112
#define SZ_STATS  ((size_t)N_STATS*8)
#define OFF_AB    (OFF_STATS + SZ_STATS)
#define SZ_AB     4096ull
#define OFF_KPART (OFF_AB + SZ_AB)
#define NKBLK     2048
#define SZ_KPART  ((size_t)9*NKBLK*4)
#define OFF_YMM   (OFF_KPART + SZ_KPART)
#define SZ_YMM    ((size_t)DIM*NBLK*32*4)      // 33,554,432

// stats (f64) indices
#define I_S2   16
#define I_S3   (16 + 8*256)
#define NBANK  8

// ab (float) layout
#define AB_W1F 0
#define AB_A2  512
#define AB_E2  640
#define AB_A3  768
#define AB_E3  896

__device__ __forceinline__ void atomAddD(double* p, double v) {
    __hip_atomic_fetch_add(p, v, __ATOMIC_RELAXED, __HIP_MEMORY_SCOPE_AGENT);
}
__device__ __forceinline__ unsigned short f2bs(float f) {
    const unsigned b = __float_as_uint(f);
    return (unsigned short)((b + 0x7FFFu + ((b >> 16) & 1u)) >> 16);   // RNE
}
__device__ __forceinline__ float bs2f(unsigned short u) {
    return __uint_as_float(((unsigned)u) << 16);
}

// ---------------------------------------------------------------------------
__global__ void zero_stats_kernel(double* __restrict__ st) {
    for (int i = threadIdx.x; i < N_STATS; i += 256) st[i] = 0.0;
}

// W2/W3 f32 [d][c] -> bf16 [d][c]
__global__ __launch_bounds__(256) void castW_kernel(
    const float* __restrict__ W2, const float* __restrict__ W3,
    unsigned short* __restrict__ Wb2, unsigned short* __restrict__ Wb3)
{
    const int i = blockIdx.x * 256 + threadIdx.x;   // 0..16383
    Wb2[i] = f2bs(W2[i]);
    Wb3[i] = f2bs(W3[i]);
}

// ---------------------------------------------------------------------------
// kNN + grouped offsets + layer-1 moment partials.
// Block = 1024 threads = 16 waves = 16 points; wave = one point.
// Distance arithmetic bit-identical to passing rounds 1-7.
__global__ __launch_bounds__(1024) void knn_group_kernel(
    const float* __restrict__ x, float* __restrict__ g, float* __restrict__ kpart)
{
    __shared__ __align__(16) float4 xs4[N_];   // 32 KB {x,y,z,|x|^2}
    __shared__ float listD[16][CAP];           // 8 KB
    __shared__ int   listI[16][CAP];           // 8 KB
    __shared__ float spart[16][12];
    const int b   = blockIdx.y;
    const int tid = threadIdx.x;
    const int wv  = tid >> 6;
    const int ln  = tid & 63;
    const int n   = blockIdx.x * 16 + wv;
    const float* xb = x + (size_t)b * 3 * N_;

    for (int i = tid; i < N_; i += 1024) {
        const float a0 = xb[i], a1 = xb[N_ + i], a2 = xb[2*N_ + i];
        const float sq = __fadd_rn(__fadd_rn(__fmul_rn(a0,a0), __fmul_rn(a1,a1)), __fmul_rn(a2,a2));
        xs4[i] = make_float4(a0, a1, a2, sq);
    }
    __syncthreads();

    const float4 me = xs4[n];
    const float xn0 = me.x, xn1 = me.y, xn2 = me.z, sqn = me.w;

    // ---- Pass A: distances in registers (1 b128 per candidate) + lane min
    float dreg[32];
    float lmin = INFINITY;
    #pragma unroll
    for (int i = 0; i < 32; ++i) {
        const float4 q = xs4[ln + 64*i];
        dreg[i] = __fadd_rn(__fmaf_rn(-2.f, __fmaf_rn(xn2, q.z, __fmaf_rn(xn1, q.y, __fmul_rn(xn0, q.x))), sqn), q.w);
        lmin = fminf(lmin, dreg[i]);
    }

    // ---- bound B' = max over 8 groups of (min over 8 lanes' minima)
    // 8 distinct candidates <= B'  =>  8th-smallest <= B'.
    float gm = lmin;
    gm = fminf(gm, __shfl_xor(gm, 1));
    gm = fminf(gm, __shfl_xor(gm, 2));
    gm = fminf(gm, __shfl_xor(gm, 4));
    float Bb = gm;
    Bb = fmaxf(Bb, __shfl_xor(Bb, 8));
    Bb = fmaxf(Bb, __shfl_xor(Bb, 16));
    Bb = fmaxf(Bb, __shfl_xor(Bb, 32));

    // ---- Pass B: ballot-compact candidates with d <= B'
    unsigned base = 0;
    #pragma unroll
    for (int i = 0; i < 32; ++i) {
        const bool pred = (dreg[i] <= Bb);
        const unsigned long long mk = __ballot(pred);
        if (pred) {
            const unsigned pos = base + (unsigned)__popcll(mk & ((1ull << ln) - 1ull));
            if (pos < CAP) { listD[wv][pos] = dreg[i]; listI[wv][pos] = ln + 64*i; }
        }
        base += (unsigned)__popcll(mk);
    }
    const int cnt = (base < CAP) ? (int)base : CAP;

    // ---- Pass C: ballot radix-select of the lex-smallest 8 (d, idx) keys.
    // key = orderable(dist) << 11 | idx  (43 bits, unique per candidate).
    const bool valid0 = (ln < cnt);
    const bool valid1 = (ln + 64 < cnt);
    float d0v = valid0 ? listD[wv][ln] : 0.f;
    int   ci0 = valid0 ? listI[wv][ln] : 0;
    float d1v = valid1 ? listD[wv][ln + 64] : 0.f;
    int   ci1 = valid1 ? listI[wv][ln + 64] : 0;
    unsigned long long K0 = ~0ull, K1 = ~0ull;
    {
        unsigned u0 = __float_as_uint(d0v);
        unsigned od0 = u0 ^ (unsigned)((((int)u0) >> 31) | 0x80000000);
        if (valid0) K0 = (((unsigned long long)od0) << 11) | (unsigned)ci0;
        unsigned u1 = __float_as_uint(d1v);
        unsigned od1 = u1 ^ (unsigned)((((int)u1) >> 31) | 0x80000000);
        if (valid1) K1 = (((unsigned long long)od1) << 11) | (unsigned)ci1;
    }
    bool race0 = valid0, race1 = valid1, sel0 = false, sel1 = false;
    int need = 8;
    #pragma unroll 1
    for (int bp = 42; bp >= 0; --bp) {
        const bool z0 = race0 && !((K0 >> bp) & 1ull);
        const bool z1 = race1 && !((K1 >> bp) & 1ull);
        const int c0 = __popcll(__ballot(z0)) + __popcll(__ballot(z1));
        if (c0 >= need) {            // wave-uniform branch
            race0 = z0; race1 = z1;
        } else {
            need -= c0;
            sel0 = sel0 || z0; sel1 = sel1 || z1;
            race0 = race0 && !z0; race1 = race1 && !z1;
        }
    }
    sel0 = sel0 || race0;            // remaining race = exactly `need`(=1) key
    sel1 = sel1 || race1;

    // ---- route the 8 winners' candidate indices to lanes 0..7
    const unsigned long long m0 = __ballot(sel0);
    const unsigned long long m1 = __ballot(sel1);
    const int n0 = __popcll(m0);
    // lane j<8 finds the j-th winner (slot-major order; order within k is
    // irrelevant downstream - max/sum over k are permutation-invariant)
    unsigned long long mm = (ln < n0) ? m0 : m1;
    int rem = (ln < n0) ? ln : (ln - n0);
    int pos = 0;
    #pragma unroll
    for (int w = 32; w >= 1; w >>= 1) {
        const unsigned long long window = (((w < 64) ? ((1ull << w) - 1ull) : ~0ull) << pos);
        const int c = __popcll(mm & window);
        if (rem >= c) { rem -= c; pos += w; }
    }
    const int idxA = __shfl(ci0, pos);
    const int idxB = __shfl(ci1, pos);
    const int myi = (ln < n0) ? idxA : idxB;

    // ---- gather, g-write, stats (lanes 0..7 hold the 8 neighbors)
    if (ln < 8) {
        const float4 q = xs4[myi];
        const float g0  = q.x - xn0;
        const float g1v = q.y - xn1;
        const float g2v = q.z - xn2;
        const size_t basep = ((size_t)b*N_ + n) * KNN;
        g[0*P_ + basep + ln] = g0;
        g[1*P_ + basep + ln] = g1v;
        g[2*P_ + basep + ln] = g2v;
        float s0 = g0, s1 = g1v, s2 = g2v;
        float s00 = g0*g0, s01 = g0*g1v, s02 = g0*g2v;
        float s11 = g1v*g1v, s12 = g1v*g2v, s22 = g2v*g2v;
        #pragma unroll
        for (int m = 1; m < 8; m <<= 1) {
            s0 += __shfl_xor(s0, m);  s1 += __shfl_xor(s1, m);  s2 += __shfl_xor(s2, m);
            s00 += __shfl_xor(s00, m); s01 += __shfl_xor(s01, m); s02 += __shfl_xor(s02, m);
            s11 += __shfl_xor(s11, m); s12 += __shfl_xor(s12, m); s22 += __shfl_xor(s22, m);
        }
        if (ln == 0) {
            spart[wv][0] = s0;  spart[wv][1] = s1;  spart[wv][2] = s2;
            spart[wv][3] = s00; spart[wv][4] = s01; spart[wv][5] = s02;
            spart[wv][6] = s11; spart[wv][7] = s12; spart[wv][8] = s22;
        }
    }
    __syncthreads();
    if (tid < 9) {
        float a = 0.f;
        #pragma unroll
        for (int w = 0; w < 16; ++w) a += spart[w][tid];
        kpart[tid*NKBLK + blockIdx.y*128 + blockIdx.x] = a;
    }
}

// ---------------------------------------------------------------------------
__global__ __launch_bounds__(128) void finalize1_kernel(
    const float* __restrict__ kpart, const float* __restrict__ W1,
    const float* __restrict__ b1, const float* __restrict__ g1,
    const float* __restrict__ be1, float* __restrict__ ab)
{
    __shared__ double red[128];
    __shared__ double S9[9];
    const int tid = threadIdx.x;
    for (int m = 0; m < 9; ++m) {
        double a = 0.0;
        for (int i = tid; i < NKBLK; i += 128) a += (double)kpart[m*NKBLK + i];
        red[tid] = a;
        __syncthreads();
        if (tid == 0) {
            double s = 0.0;
            for (int j = 0; j < 128; ++j) s += red[j];
            S9[m] = s;
        }
        __syncthreads();
    }
    const int d = tid;
    const double inv = 1.0 / (double)P_;
    const double mu0 = S9[0]*inv, mu1 = S9[1]*inv, mu2 = S9[2]*inv;
    const double c00 = S9[3]*inv - mu0*mu0;
    const double c01 = S9[4]*inv - mu0*mu1;
    const double c02 = S9[5]*inv - mu0*mu2;
    const double c11 = S9[6]*inv - mu1*mu1;
    const double c12 = S9[7]*inv - mu1*mu2;
    const double c22 = S9[8]*inv - mu2*mu2;
    const double w0 = W1[d*3+0], w1 = W1[d*3+1], w2 = W1[d*3+2];
    const double mean = w0*mu0 + w1*mu1 + w2*mu2 + (double)b1[d];
    double var = w0*w0*c00 + w1*w1*c11 + w2*w2*c22
               + 2.0*(w0*w1*c01 + w0*w2*c02 + w1*w2*c12);
    if (var < 0.0) var = 0.0;
    const double r = 1.0 / sqrt(var + 1e-5);
    const double alpha = (double)g1[d] * r;
    const double beta  = (double)be1[d] - mean*alpha;
    ab[AB_W1F + 4*d + 0] = (float)(alpha * w0);
    ab[AB_W1F + 4*d + 1] = (float)(alpha * w1);
    ab[AB_W1F + 4*d + 2] = (float)(alpha * w2);
    ab[AB_W1F + 4*d + 3] = (float)(alpha * (double)b1[d] + beta);
}

__global__ void finalize23_kernel(
    const double* __restrict__ st, int soff,
    const float* __restrict__ gg, const float* __restrict__ bee,
    float* __restrict__ ab, int aoff)
{
    const int d = threadIdx.x;
    if (d >= DIM) return;
    double s1 = 0.0, s2 = 0.0;
    #pragma unroll
    for (int k = 0; k < NBANK; ++k) {
        s1 += st[soff + k*256 + d];
        s2 += st[soff + k*256 + 128 + d];
    }
    const double inv = 1.0 / (double)P_;
    const double mean = s1 * inv;
    double var = s2 * inv - mean*mean;
    if (var < 0.0) var = 0.0;
    const double r = 1.0 / sqrt(var + 1e-5);
    const double alpha = (double)gg[d] * r;
    ab[aoff + d]       = (float)alpha;
    ab[aoff + 128 + d] = (float)((double)bee[d] - mean*alpha);
}

// ---------------------------------------------------------------------------
// MFMA conv (round-7 proven): block = 128d x 128p, 4 waves; wave w owns
// d in [32w,32w+32). Ht[p][c] bf16 in LDS, c-octet XOR(p&7) swizzle.
// A-frags preloaded from global bf16 W[d][c]. mfma_f32_16x16x32_bf16.
// SRC 0: H from g via folded W1f (conv2).  SRC 1: H = relu(a2*y2b+e2) (conv3).
// MODE 0: y2b (bf16) + stats.  MODE 3: stats + per-point max/min -> ymm.
template<int SRC, int MODE>
__global__ __launch_bounds__(256) void conv_kernel(
    const float* __restrict__ gsrc, const unsigned short* __restrict__ ybsrc,
    const unsigned short* __restrict__ Wb, const float* __restrict__ ab,
    const float* __restrict__ bias, unsigned short* __restrict__ ybdst,
    float* __restrict__ ymm, double* __restrict__ stats, int statoff)
{
    __shared__ __align__(16) short Hs[128*128];   // 32 KB, Ht[p][c] swizzled
    const int tid = threadIdx.x;
    const int p0g = blockIdx.x * 128;
    const int w  = tid >> 6, ln = tid & 63;
    const int lg = ln >> 4, lr = ln & 15;

    bf16x8 afrag[2][4];
    #pragma unroll
    for (int dtl = 0; dtl < 2; ++dtl)
        #pragma unroll
        for (int ks = 0; ks < 4; ++ks)
            afrag[dtl][ks] = *(const bf16x8*)&Wb[(32*w + 16*dtl + lr)*DIM + (4*ks + lg)*8];

    const int sp = 64*(w & 1) + ln;     // 0..127
    const int ob = w >> 1;              // 0 or 1
    if constexpr (SRC == 0) {
        const float gx = gsrc[0*P_ + p0g + sp];
        const float gy = gsrc[1*P_ + p0g + sp];
        const float gz = gsrc[2*P_ + p0g + sp];
        #pragma unroll
        for (int it = 0; it < 8; ++it) {
            const int o = ob + 2*it;
            bf16x8 hv;
            #pragma unroll
            for (int j = 0; j < 8; ++j) {
                const int c = 8*o + j;
                const float4 wf = *(const float4*)&ab[AB_W1F + 4*c];
                const float h = fmaxf(__fmaf_rn(wf.x, gx, __fmaf_rn(wf.y, gy, __fmaf_rn(wf.z, gz, wf.w))), 0.f);
                hv[j] = (short)f2bs(h);
            }
            *(bf16x8*)&Hs[sp*128 + ((o ^ (sp & 7)) * 8)] = hv;
        }
    } else {
        #pragma unroll
        for (int it = 0; it < 8; ++it) {
            const int o = ob + 2*it;
            bf16x8 hv;
            #pragma unroll
            for (int j = 0; j < 8; ++j) {
                const int c = 8*o + j;
                const float v = bs2f(ybsrc[(size_t)c*P_ + p0g + sp]);
                const float h = fmaxf(__fmaf_rn(ab[AB_A2 + c], v, ab[AB_E2 + c]), 0.f);
                hv[j] = (short)f2bs(h);
            }
            *(bf16x8*)&Hs[sp*128 + ((o ^ (sp & 7)) * 8)] = hv;
        }
    }
    __syncthreads();

    f32x4 acc[2][8];
    #pragma unroll
    for (int i = 0; i < 2; ++i)
        #pragma unroll
        for (int j = 0; j < 8; ++j)
            acc[i][j] = (f32x4){0.f, 0.f, 0.f, 0.f};

    #pragma unroll
    for (int ks = 0; ks < 4; ++ks) {
        #pragma unroll
        for (int pt = 0; pt < 8; ++pt) {
            const int p = 16*pt + lr;
            const bf16x8 bf = *(const bf16x8*)&Hs[p*128 + (((4*ks + lg) ^ (lr & 7)) * 8)];
            acc[0][pt] = __builtin_amdgcn_mfma_f32_16x16x32_bf16(afrag[0][ks], bf, acc[0][pt], 0, 0, 0);
            acc[1][pt] = __builtin_amdgcn_mfma_f32_16x16x32_bf16(afrag[1][ks], bf, acc[1][pt], 0, 0, 0);
        }
    }

    const int bank = blockIdx.x & (NBANK-1);
    #pragma unroll
    for (int dtl = 0; dtl < 2; ++dtl) {
        #pragma unroll
        for (int r = 0; r < 4; ++r) {
            const int d = 32*w + 16*dtl + 4*lg + r;
            const float bb = bias[d];
            float v[8];
            #pragma unroll
            for (int pt = 0; pt < 8; ++pt) v[pt] = acc[dtl][pt][r] + bb;

            if constexpr (MODE == 0) {
                #pragma unroll
                for (int pt = 0; pt < 8; ++pt)
                    ybdst[(size_t)d*P_ + p0g + 16*pt + lr] = f2bs(v[pt]);
            }

            float s1 = ((v[0]+v[1])+(v[2]+v[3])) + ((v[4]+v[5])+(v[6]+v[7]));
            float s2 = ((v[0]*v[0]+v[1]*v[1])+(v[2]*v[2]+v[3]*v[3]))
                     + ((v[4]*v[4]+v[5]*v[5])+(v[6]*v[6]+v[7]*v[7]));
            #pragma unroll
            for (int m = 1; m < 16; m <<= 1) { s1 += __shfl_xor(s1, m); s2 += __shfl_xor(s2, m); }
            if (lr == 0) {
                atomAddD(&stats[statoff + bank*256 + d], (double)s1);
                atomAddD(&stats[statoff + bank*256 + 128 + d], (double)s2);
            }

            if constexpr (MODE == 3) {
                #pragma unroll
                for (int pt = 0; pt < 8; ++pt) {
                    float mx = v[pt], mn = v[pt];
                    float o1 = __shfl_xor(mx, 1); mx = fmaxf(mx, o1); mn = fminf(mn, o1);
                    float o2x = __shfl_xor(mx, 2), o2n = __shfl_xor(mn, 2);
                    mx = fmaxf(mx, o2x); mn = fminf(mn, o2n);
                    float o4x = __shfl_xor(mx, 4), o4n = __shfl_xor(mn, 4);
                    mx = fmaxf(mx, o4x); mn = fminf(mn, o4n);
                    if ((lr & 7) == 0) {
                        const int slot = 2*pt + (lr >> 3);
                        float* yb = ymm + ((size_t)d*NBLK + blockIdx.x)*32;
                        yb[slot]      = mx;
                        yb[16 + slot] = mn;
                    }
                }
            }
        }
    }
}

// ---------------------------------------------------------------------------
// Epilogue: out[b,d,n] = relu(a3*(a3>=0 ? max_k : min_k) + e3)
__global__ __launch_bounds__(256) void bn3max_kernel(
    const float* __restrict__ ymm, const float* __restrict__ ab, float* __restrict__ out)
{
    const int idx = blockIdx.x*256 + threadIdx.x;   // over B*DIM*N
    const int n = idx & (N_-1);
    const int d = (idx >> 11) & (DIM-1);
    const int b = idx >> 18;
    const int pt  = b*N_ + n;
    const int blk = pt >> 4;
    const int j   = pt & 15;
    const size_t base = ((size_t)d*NBLK + blk) * 32;
    const float a = ab[AB_A3 + d], e = ab[AB_E3 + d];
    const float mx = ymm[base + j];
    const float mn = ymm[base + 16 + j];
    const float v = (a >= 0.f) ? mx : mn;
    out[idx] = fmaxf(__fmaf_rn(a, v, e), 0.f);
}

// ---------------------------------------------------------------------------
extern "C" void kernel_launch(void* const* d_in, const int* in_sizes, int n_in,
                              void* d_out, int out_size, void* d_ws, size_t ws_size,
                              hipStream_t stream) {
    (void)in_sizes; (void)n_in; (void)out_size; (void)ws_size;
    const float* x   = (const float*)d_in[0];
    const float* W1  = (const float*)d_in[1];
    const float* b1  = (const float*)d_in[2];
    const float* g1  = (const float*)d_in[3];
    const float* be1 = (const float*)d_in[4];
    const float* W2  = (const float*)d_in[5];
    const float* b2  = (const float*)d_in[6];
    const float* g2  = (const float*)d_in[7];
    const float* be2 = (const float*)d_in[8];
    const float* W3  = (const float*)d_in[9];
    const float* b3  = (const float*)d_in[10];
    const float* g3  = (const float*)d_in[11];
    const float* be3 = (const float*)d_in[12];

    float*  out = (float*)d_out;
    char*   ws  = (char*)d_ws;
    float*          g   = (float*)(ws + OFF_G);
    unsigned short* y2b = (unsigned short*)(ws + OFF_Y2B);
    unsigned short* wb2 = (unsigned short*)(ws + OFF_WB2);
    unsigned short* wb3 = (unsigned short*)(ws + OFF_WB3);
    double*         st  = (double*)(ws + OFF_STATS);
    float*          ab  = (float*)(ws + OFF_AB);
    float*          kp  = (float*)(ws + OFF_KPART);
    float*          ymm = (float*)(ws + OFF_YMM);

    zero_stats_kernel<<<1, 256, 0, stream>>>(st);
    castW_kernel<<<64, 256, 0, stream>>>(W2, W3, wb2, wb3);
    knn_group_kernel<<<dim3(128, B_), 1024, 0, stream>>>(x, g, kp);
    finalize1_kernel<<<1, 128, 0, stream>>>(kp, W1, b1, g1, be1, ab);
    conv_kernel<0,0><<<NBLK, 256, 0, stream>>>(g, nullptr, wb2, ab, b2, y2b, nullptr, st, I_S2);
    finalize23_kernel<<<1, 128, 0, stream>>>(st, I_S2, g2, be2, ab, AB_A2);
    conv_kernel<1,3><<<NBLK, 256, 0, stream>>>(nullptr, y2b, wb3, ab, b3, nullptr, ymm, st, I_S3);
    finalize23_kernel<<<1, 128, 0, stream>>>(st, I_S3, g3, be3, ab, AB_A3);
    bn3max_kernel<<<(B_*DIM*N_)/256, 256, 0, stream>>>(ymm, ab, out);
}

// Round 9
// 259.526 us; speedup vs baseline: 1.2203x; 1.2203x over previous
//
#include <hip/hip_runtime.h>
#include <hip/hip_bf16.h>
#include <math.h>

// ---------------------------------------------------------------------------
// FeatureNet (DGCNN edge-conv block), MI355X / gfx950, round 9.
//
// Round-9 change (kNN only; convs = round-7/8 MFMA versions):
//  * Keep r8's float4 Pass A (1 ds_read_b128/candidate) and cheap bound
//    (max of 8 group minima, 6 shuffles).
//  * REVERT Pass C to r7's shuffle-based 8x lex-argmin (the r8 ballot
//    radix-select was a serial scalar chain: 92 -> 131 us regression).
// ---------------------------------------------------------------------------

#define B_   16
#define N_   2048
#define KNN  8
#define DIM  128
#define P_   (B_*N_*KNN)   // 262144
#define CAP  128
#define NBLK 2048          // conv blocks (128 p each)

typedef __attribute__((ext_vector_type(8))) short bf16x8;
typedef __attribute__((ext_vector_type(4))) float f32x4;

// ws layout (bytes)
#define OFF_G     0ull
#define SZ_G      ((size_t)3*P_*4)             // 3,145,728
#define OFF_Y2B   (OFF_G + SZ_G)
#define SZ_Y2B    ((size_t)DIM*P_*2)           // 67,108,864
#define OFF_WB2   (OFF_Y2B + SZ_Y2B)
#define SZ_WB     ((size_t)DIM*DIM*2)          // 32,768
#define OFF_WB3   (OFF_WB2 + SZ_WB)
#define OFF_STATS (OFF_WB3 + SZ_WB)
#define N_STATS   4112
#define SZ_STATS  ((size_t)N_STATS*8)
#define OFF_AB    (OFF_STATS + SZ_STATS)
#define SZ_AB     4096ull
#define OFF_KPART (OFF_AB + SZ_AB)
#define NKBLK     2048
#define SZ_KPART  ((size_t)9*NKBLK*4)
#define OFF_YMM   (OFF_KPART + SZ_KPART)
#define SZ_YMM    ((size_t)DIM*NBLK*32*4)      // 33,554,432

// stats (f64) indices
#define I_S2   16
#define I_S3   (16 + 8*256)
#define NBANK  8

// ab (float) layout
#define AB_W1F 0
#define AB_A2  512
#define AB_E2  640
#define AB_A3  768
#define AB_E3  896

__device__ __forceinline__ void atomAddD(double* p, double v) {
    __hip_atomic_fetch_add(p, v, __ATOMIC_RELAXED, __HIP_MEMORY_SCOPE_AGENT);
}
__device__ __forceinline__ unsigned short f2bs(float f) {
    const unsigned b = __float_as_uint(f);
    return (unsigned short)((b + 0x7FFFu + ((b >> 16) & 1u)) >> 16);   // RNE
}
__device__ __forceinline__ float bs2f(unsigned short u) {
    return __uint_as_float(((unsigned)u) << 16);
}

// ---------------------------------------------------------------------------
__global__ void zero_stats_kernel(double* __restrict__ st) {
    for (int i = threadIdx.x; i < N_STATS; i += 256) st[i] = 0.0;
}

// W2/W3 f32 [d][c] -> bf16 [d][c]
__global__ __launch_bounds__(256) void castW_kernel(
    const float* __restrict__ W2, const float* __restrict__ W3,
    unsigned short* __restrict__ Wb2, unsigned short* __restrict__ Wb3)
{
    const int i = blockIdx.x * 256 + threadIdx.x;   // 0..16383
    Wb2[i] = f2bs(W2[i]);
    Wb3[i] = f2bs(W3[i]);
}

// ---------------------------------------------------------------------------
// kNN + grouped offsets + layer-1 moment partials.
// Block = 1024 threads = 16 waves = 16 points; wave = one point.
// Distance arithmetic bit-identical to passing rounds 1-8.
__global__ __launch_bounds__(1024) void knn_group_kernel(
    const float* __restrict__ x, float* __restrict__ g, float* __restrict__ kpart)
{
    __shared__ __align__(16) float4 xs4[N_];   // 32 KB {x,y,z,|x|^2}
    __shared__ float listD[16][CAP];           // 8 KB
    __shared__ int   listI[16][CAP];           // 8 KB
    __shared__ float spart[16][12];
    const int b   = blockIdx.y;
    const int tid = threadIdx.x;
    const int wv  = tid >> 6;
    const int ln  = tid & 63;
    const int n   = blockIdx.x * 16 + wv;
    const float* xb = x + (size_t)b * 3 * N_;

    for (int i = tid; i < N_; i += 1024) {
        const float a0 = xb[i], a1 = xb[N_ + i], a2 = xb[2*N_ + i];
        const float sq = __fadd_rn(__fadd_rn(__fmul_rn(a0,a0), __fmul_rn(a1,a1)), __fmul_rn(a2,a2));
        xs4[i] = make_float4(a0, a1, a2, sq);
    }
    __syncthreads();

    const float4 me = xs4[n];
    const float xn0 = me.x, xn1 = me.y, xn2 = me.z, sqn = me.w;

    // ---- Pass A: distances in registers (1 b128 per candidate) + lane min
    float dreg[32];
    float lmin = INFINITY;
    #pragma unroll
    for (int i = 0; i < 32; ++i) {
        const float4 q = xs4[ln + 64*i];
        dreg[i] = __fadd_rn(__fmaf_rn(-2.f, __fmaf_rn(xn2, q.z, __fmaf_rn(xn1, q.y, __fmul_rn(xn0, q.x))), sqn), q.w);
        lmin = fminf(lmin, dreg[i]);
    }

    // ---- bound B' = max over 8 groups of (min over each 8-lane group)
    // 8 distinct candidates <= B'  =>  8th-smallest <= B'.
    float gm = lmin;
    gm = fminf(gm, __shfl_xor(gm, 1));
    gm = fminf(gm, __shfl_xor(gm, 2));
    gm = fminf(gm, __shfl_xor(gm, 4));
    float Bb = gm;
    Bb = fmaxf(Bb, __shfl_xor(Bb, 8));
    Bb = fmaxf(Bb, __shfl_xor(Bb, 16));
    Bb = fmaxf(Bb, __shfl_xor(Bb, 32));

    // ---- Pass B: ballot-compact candidates with d <= B'
    unsigned base = 0;
    #pragma unroll
    for (int i = 0; i < 32; ++i) {
        const bool pred = (dreg[i] <= Bb);
        const unsigned long long mk = __ballot(pred);
        if (pred) {
            const unsigned pos = base + (unsigned)__popcll(mk & ((1ull << ln) - 1ull));
            if (pos < CAP) { listD[wv][pos] = dreg[i]; listI[wv][pos] = ln + 64*i; }
        }
        base += (unsigned)__popcll(mk);
    }
    const int cnt = (base < CAP) ? (int)base : CAP;

    // ---- Pass C (r7-proven): 8x wave lex-argmin over compacted list
    // == exact lax.top_k selection (stable ties).
    float cd0 = (ln < cnt)      ? listD[wv][ln]      : INFINITY;
    int   ci0 = (ln < cnt)      ? listI[wv][ln]      : 0x7FFFFFFF;
    float cd1 = (ln + 64 < cnt) ? listD[wv][ln + 64] : INFINITY;
    int   ci1 = (ln + 64 < cnt) ? listI[wv][ln + 64] : 0x7FFFFFFF;
    int myi = 0;   // lane ln<8 ends up with neighbor index of rank ln
    #pragma unroll
    for (int sel = 0; sel < 8; ++sel) {
        const bool sw = (cd1 < cd0) || (cd1 == cd0 && ci1 < ci0);
        float pd = sw ? cd1 : cd0;
        int   pi = sw ? ci1 : ci0;
        #pragma unroll
        for (int m = 1; m < 64; m <<= 1) {
            const float od = __shfl_xor(pd, m);
            const int   oi = __shfl_xor(pi, m);
            if ((od < pd) || (od == pd && oi < pi)) { pd = od; pi = oi; }
        }
        myi = (ln == sel) ? pi : myi;
        if (ci0 == pi) cd0 = INFINITY;
        if (ci1 == pi) cd1 = INFINITY;
    }

    // ---- gather, g-write, stats (lanes 0..7 hold the 8 neighbors)
    if (ln < 8) {
        const float4 q = xs4[myi];
        const float g0  = q.x - xn0;
        const float g1v = q.y - xn1;
        const float g2v = q.z - xn2;
        const size_t basep = ((size_t)b*N_ + n) * KNN;
        g[0*P_ + basep + ln] = g0;
        g[1*P_ + basep + ln] = g1v;
        g[2*P_ + basep + ln] = g2v;
        float s0 = g0, s1 = g1v, s2 = g2v;
        float s00 = g0*g0, s01 = g0*g1v, s02 = g0*g2v;
        float s11 = g1v*g1v, s12 = g1v*g2v, s22 = g2v*g2v;
        #pragma unroll
        for (int m = 1; m < 8; m <<= 1) {
            s0 += __shfl_xor(s0, m);  s1 += __shfl_xor(s1, m);  s2 += __shfl_xor(s2, m);
            s00 += __shfl_xor(s00, m); s01 += __shfl_xor(s01, m); s02 += __shfl_xor(s02, m);
            s11 += __shfl_xor(s11, m); s12 += __shfl_xor(s12, m); s22 += __shfl_xor(s22, m);
        }
        if (ln == 0) {
            spart[wv][0] = s0;  spart[wv][1] = s1;  spart[wv][2] = s2;
            spart[wv][3] = s00; spart[wv][4] = s01; spart[wv][5] = s02;
            spart[wv][6] = s11; spart[wv][7] = s12; spart[wv][8] = s22;
        }
    }
    __syncthreads();
    if (tid < 9) {
        float a = 0.f;
        #pragma unroll
        for (int w = 0; w < 16; ++w) a += spart[w][tid];
        kpart[tid*NKBLK + blockIdx.y*128 + blockIdx.x] = a;
    }
}

// ---------------------------------------------------------------------------
__global__ __launch_bounds__(128) void finalize1_kernel(
    const float* __restrict__ kpart, const float* __restrict__ W1,
    const float* __restrict__ b1, const float* __restrict__ g1,
    const float* __restrict__ be1, float* __restrict__ ab)
{
    __shared__ double red[128];
    __shared__ double S9[9];
    const int tid = threadIdx.x;
    for (int m = 0; m < 9; ++m) {
        double a = 0.0;
        for (int i = tid; i < NKBLK; i += 128) a += (double)kpart[m*NKBLK + i];
        red[tid] = a;
        __syncthreads();
        if (tid == 0) {
            double s = 0.0;
            for (int j = 0; j < 128; ++j) s += red[j];
            S9[m] = s;
        }
        __syncthreads();
    }
    const int d = tid;
    const double inv = 1.0 / (double)P_;
    const double mu0 = S9[0]*inv, mu1 = S9[1]*inv, mu2 = S9[2]*inv;
    const double c00 = S9[3]*inv - mu0*mu0;
    const double c01 = S9[4]*inv - mu0*mu1;
    const double c02 = S9[5]*inv - mu0*mu2;
    const double c11 = S9[6]*inv - mu1*mu1;
    const double c12 = S9[7]*inv - mu1*mu2;
    const double c22 = S9[8]*inv - mu2*mu2;
    const double w0 = W1[d*3+0], w1 = W1[d*3+1], w2 = W1[d*3+2];
    const double mean = w0*mu0 + w1*mu1 + w2*mu2 + (double)b1[d];
    double var = w0*w0*c00 + w1*w1*c11 + w2*w2*c22
               + 2.0*(w0*w1*c01 + w0*w2*c02 + w1*w2*c12);
    if (var < 0.0) var = 0.0;
    const double r = 1.0 / sqrt(var + 1e-5);
    const double alpha = (double)g1[d] * r;
    const double beta  = (double)be1[d] - mean*alpha;
    ab[AB_W1F + 4*d + 0] = (float)(alpha * w0);
    ab[AB_W1F + 4*d + 1] = (float)(alpha * w1);
    ab[AB_W1F + 4*d + 2] = (float)(alpha * w2);
    ab[AB_W1F + 4*d + 3] = (float)(alpha * (double)b1[d] + beta);
}

__global__ void finalize23_kernel(
    const double* __restrict__ st, int soff,
    const float* __restrict__ gg, const float* __restrict__ bee,
    float* __restrict__ ab, int aoff)
{
    const int d = threadIdx.x;
    if (d >= DIM) return;
    double s1 = 0.0, s2 = 0.0;
    #pragma unroll
    for (int k = 0; k < NBANK; ++k) {
        s1 += st[soff + k*256 + d];
        s2 += st[soff + k*256 + 128 + d];
    }
    const double inv = 1.0 / (double)P_;
    const double mean = s1 * inv;
    double var = s2 * inv - mean*mean;
    if (var < 0.0) var = 0.0;
    const double r = 1.0 / sqrt(var + 1e-5);
    const double alpha = (double)gg[d] * r;
    ab[aoff + d]       = (float)alpha;
    ab[aoff + 128 + d] = (float)((double)bee[d] - mean*alpha);
}

// ---------------------------------------------------------------------------
// MFMA conv (round-7 proven): block = 128d x 128p, 4 waves; wave w owns
// d in [32w,32w+32). Ht[p][c] bf16 in LDS, c-octet XOR(p&7) swizzle.
// A-frags preloaded from global bf16 W[d][c]. mfma_f32_16x16x32_bf16.
// SRC 0: H from g via folded W1f (conv2).  SRC 1: H = relu(a2*y2b+e2) (conv3).
// MODE 0: y2b (bf16) + stats.  MODE 3: stats + per-point max/min -> ymm.
template<int SRC, int MODE>
__global__ __launch_bounds__(256) void conv_kernel(
    const float* __restrict__ gsrc, const unsigned short* __restrict__ ybsrc,
    const unsigned short* __restrict__ Wb, const float* __restrict__ ab,
    const float* __restrict__ bias, unsigned short* __restrict__ ybdst,
    float* __restrict__ ymm, double* __restrict__ stats, int statoff)
{
    __shared__ __align__(16) short Hs[128*128];   // 32 KB, Ht[p][c] swizzled
    const int tid = threadIdx.x;
    const int p0g = blockIdx.x * 128;
    const int w  = tid >> 6, ln = tid & 63;
    const int lg = ln >> 4, lr = ln & 15;

    bf16x8 afrag[2][4];
    #pragma unroll
    for (int dtl = 0; dtl < 2; ++dtl)
        #pragma unroll
        for (int ks = 0; ks < 4; ++ks)
            afrag[dtl][ks] = *(const bf16x8*)&Wb[(32*w + 16*dtl + lr)*DIM + (4*ks + lg)*8];

    const int sp = 64*(w & 1) + ln;     // 0..127
    const int ob = w >> 1;              // 0 or 1
    if constexpr (SRC == 0) {
        const float gx = gsrc[0*P_ + p0g + sp];
        const float gy = gsrc[1*P_ + p0g + sp];
        const float gz = gsrc[2*P_ + p0g + sp];
        #pragma unroll
        for (int it = 0; it < 8; ++it) {
            const int o = ob + 2*it;
            bf16x8 hv;
            #pragma unroll
            for (int j = 0; j < 8; ++j) {
                const int c = 8*o + j;
                const float4 wf = *(const float4*)&ab[AB_W1F + 4*c];
                const float h = fmaxf(__fmaf_rn(wf.x, gx, __fmaf_rn(wf.y, gy, __fmaf_rn(wf.z, gz, wf.w))), 0.f);
                hv[j] = (short)f2bs(h);
            }
            *(bf16x8*)&Hs[sp*128 + ((o ^ (sp & 7)) * 8)] = hv;
        }
    } else {
        #pragma unroll
        for (int it = 0; it < 8; ++it) {
            const int o = ob + 2*it;
            bf16x8 hv;
            #pragma unroll
            for (int j = 0; j < 8; ++j) {
                const int c = 8*o + j;
                const float v = bs2f(ybsrc[(size_t)c*P_ + p0g + sp]);
                const float h = fmaxf(__fmaf_rn(ab[AB_A2 + c], v, ab[AB_E2 + c]), 0.f);
                hv[j] = (short)f2bs(h);
            }
            *(bf16x8*)&Hs[sp*128 + ((o ^ (sp & 7)) * 8)] = hv;
        }
    }
    __syncthreads();

    f32x4 acc[2][8];
    #pragma unroll
    for (int i = 0; i < 2; ++i)
        #pragma unroll
        for (int j = 0; j < 8; ++j)
            acc[i][j] = (f32x4){0.f, 0.f, 0.f, 0.f};

    #pragma unroll
    for (int ks = 0; ks < 4; ++ks) {
        #pragma unroll
        for (int pt = 0; pt < 8; ++pt) {
            const int p = 16*pt + lr;
            const bf16x8 bf = *(const bf16x8*)&Hs[p*128 + (((4*ks + lg) ^ (lr & 7)) * 8)];
            acc[0][pt] = __builtin_amdgcn_mfma_f32_16x16x32_bf16(afrag[0][ks], bf, acc[0][pt], 0, 0, 0);
            acc[1][pt] = __builtin_amdgcn_mfma_f32_16x16x32_bf16(afrag[1][ks], bf, acc[1][pt], 0, 0, 0);
        }
    }

    const int bank = blockIdx.x & (NBANK-1);
    #pragma unroll
    for (int dtl = 0; dtl < 2; ++dtl) {
        #pragma unroll
        for (int r = 0; r < 4; ++r) {
            const int d = 32*w + 16*dtl + 4*lg + r;
            const float bb = bias[d];
            float v[8];
            #pragma unroll
            for (int pt = 0; pt < 8; ++pt) v[pt] = acc[dtl][pt][r] + bb;

            if constexpr (MODE == 0) {
                #pragma unroll
                for (int pt = 0; pt < 8; ++pt)
                    ybdst[(size_t)d*P_ + p0g + 16*pt + lr] = f2bs(v[pt]);
            }

            float s1 = ((v[0]+v[1])+(v[2]+v[3])) + ((v[4]+v[5])+(v[6]+v[7]));
            float s2 = ((v[0]*v[0]+v[1]*v[1])+(v[2]*v[2]+v[3]*v[3]))
                     + ((v[4]*v[4]+v[5]*v[5])+(v[6]*v[6]+v[7]*v[7]));
            #pragma unroll
            for (int m = 1; m < 16; m <<= 1) { s1 += __shfl_xor(s1, m); s2 += __shfl_xor(s2, m); }
            if (lr == 0) {
                atomAddD(&stats[statoff + bank*256 + d], (double)s1);
                atomAddD(&stats[statoff + bank*256 + 128 + d], (double)s2);
            }

            if constexpr (MODE == 3) {
                #pragma unroll
                for (int pt = 0; pt < 8; ++pt) {
                    float mx = v[pt], mn = v[pt];
                    float o1 = __shfl_xor(mx, 1); mx = fmaxf(mx, o1); mn = fminf(mn, o1);
                    float o2x = __shfl_xor(mx, 2), o2n = __shfl_xor(mn, 2);
                    mx = fmaxf(mx, o2x); mn = fminf(mn, o2n);
                    float o4x = __shfl_xor(mx, 4), o4n = __shfl_xor(mn, 4);
                    mx = fmaxf(mx, o4x); mn = fminf(mn, o4n);
                    if ((lr & 7) == 0) {
                        const int slot = 2*pt + (lr >> 3);
                        float* yb = ymm + ((size_t)d*NBLK + blockIdx.x)*32;
                        yb[slot]      = mx;
                        yb[16 + slot] = mn;
                    }
                }
            }
        }
    }
}

// ---------------------------------------------------------------------------
// Epilogue: out[b,d,n] = relu(a3*(a3>=0 ? max_k : min_k) + e3)
__global__ __launch_bounds__(256) void bn3max_kernel(
    const float* __restrict__ ymm, const float* __restrict__ ab, float* __restrict__ out)
{
    const int idx = blockIdx.x*256 + threadIdx.x;   // over B*DIM*N
    const int n = idx & (N_-1);
    const int d = (idx >> 11) & (DIM-1);
    const int b = idx >> 18;
    const int pt  = b*N_ + n;
    const int blk = pt >> 4;
    const int j   = pt & 15;
    const size_t base = ((size_t)d*NBLK + blk) * 32;
    const float a = ab[AB_A3 + d], e = ab[AB_E3 + d];
    const float mx = ymm[base + j];
    const float mn = ymm[base + 16 + j];
    const float v = (a >= 0.f) ? mx : mn;
    out[idx] = fmaxf(__fmaf_rn(a, v, e), 0.f);
}

// ---------------------------------------------------------------------------
extern "C" void kernel_launch(void* const* d_in, const int* in_sizes, int n_in,
                              void* d_out, int out_size, void* d_ws, size_t ws_size,
                              hipStream_t stream) {
    (void)in_sizes; (void)n_in; (void)out_size; (void)ws_size;
    const float* x   = (const float*)d_in[0];
    const float* W1  = (const float*)d_in[1];
    const float* b1  = (const float*)d_in[2];
    const float* g1  = (const float*)d_in[3];
    const float* be1 = (const float*)d_in[4];
    const float* W2  = (const float*)d_in[5];
    const float* b2  = (const float*)d_in[6];
    const float* g2  = (const float*)d_in[7];
    const float* be2 = (const float*)d_in[8];
    const float* W3  = (const float*)d_in[9];
    const float* b3  = (const float*)d_in[10];
    const float* g3  = (const float*)d_in[11];
    const float* be3 = (const float*)d_in[12];

    float*  out = (float*)d_out;
    char*   ws  = (char*)d_ws;
    float*          g   = (float*)(ws + OFF_G);
    unsigned short* y2b = (unsigned short*)(ws + OFF_Y2B);
    unsigned short* wb2 = (unsigned short*)(ws + OFF_WB2);
    unsigned short* wb3 = (unsigned short*)(ws + OFF_WB3);
    double*         st  = (double*)(ws + OFF_STATS);
    float*          ab  = (float*)(ws + OFF_AB);
    float*          kp  = (float*)(ws + OFF_KPART);
    float*          ymm = (float*)(ws + OFF_YMM);

    zero_stats_kernel<<<1, 256, 0, stream>>>(st);
    castW_kernel<<<64, 256, 0, stream>>>(W2, W3, wb2, wb3);
    knn_group_kernel<<<dim3(128, B_), 1024, 0, stream>>>(x, g, kp);
    finalize1_kernel<<<1, 128, 0, stream>>>(kp, W1, b1, g1, be1, ab);
    conv_kernel<0,0><<<NBLK, 256, 0, stream>>>(g, nullptr, wb2, ab, b2, y2b, nullptr, st, I_S2);
    finalize23_kernel<<<1, 128, 0, stream>>>(st, I_S2, g2, be2, ab, AB_A2);
    conv_kernel<1,3><<<NBLK, 256, 0, stream>>>(nullptr, y2b, wb3, ab, b3, nullptr, ymm, st, I_S3);
    finalize23_kernel<<<1, 128, 0, stream>>>(st, I_S3, g3, be3, ab, AB_A3);
    bn3max_kernel<<<(B_*DIM*N_)/256, 256, 0, stream>>>(ymm, ab, out);
}

// Round 10
// 252.115 us; speedup vs baseline: 1.2562x; 1.0294x over previous
//
#include <hip/hip_runtime.h>
#include <hip/hip_bf16.h>
#include <math.h>

// ---------------------------------------------------------------------------
// FeatureNet (DGCNN edge-conv block), MI355X / gfx950, round 10.
//
// Round-10 change (convs only; kNN = round-9 proven):
//  * y2 stored p-major (y2t[p][c] bf16).
//  * conv2 epilogue: LDS transpose (stride-136 rows) -> fully coalesced
//    b128 stores of y2t (8 insts/thread vs 64 scalar u16 stores).
//  * conv3 staging: contiguous 1KB/wave b128 loads of y2t rows + in-reg
//    BN2+ReLU -> swizzled ds_write_b128 (vs 64 scalar ushort loads).
// Rationale: r9 counters showed convs latency/transaction-bound
// (MfmaUtil 4%, VALUBusy 34%, HBM 14%, 2-byte global ops dominant).
// ---------------------------------------------------------------------------

#define B_   16
#define N_   2048
#define KNN  8
#define DIM  128
#define P_   (B_*N_*KNN)   // 262144
#define CAP  128
#define NBLK 2048          // conv blocks (128 p each)

typedef __attribute__((ext_vector_type(8))) short bf16x8;
typedef __attribute__((ext_vector_type(4))) short bf16x4;
typedef __attribute__((ext_vector_type(4))) float f32x4;

// ws layout (bytes)
#define OFF_G     0ull
#define SZ_G      ((size_t)3*P_*4)             // 3,145,728
#define OFF_Y2B   (OFF_G + SZ_G)
#define SZ_Y2B    ((size_t)DIM*P_*2)           // 67,108,864  (y2t[p][c])
#define OFF_WB2   (OFF_Y2B + SZ_Y2B)
#define SZ_WB     ((size_t)DIM*DIM*2)          // 32,768
#define OFF_WB3   (OFF_WB2 + SZ_WB)
#define OFF_STATS (OFF_WB3 + SZ_WB)
#define N_STATS   4112
#define SZ_STATS  ((size_t)N_STATS*8)
#define OFF_AB    (OFF_STATS + SZ_STATS)
#define SZ_AB     4096ull
#define OFF_KPART (OFF_AB + SZ_AB)
#define NKBLK     2048
#define SZ_KPART  ((size_t)9*NKBLK*4)
#define OFF_YMM   (OFF_KPART + SZ_KPART)
#define SZ_YMM    ((size_t)DIM*NBLK*32*4)      // 33,554,432

// stats (f64) indices
#define I_S2   16
#define I_S3   (16 + 8*256)
#define NBANK  8

// ab (float) layout
#define AB_W1F 0
#define AB_A2  512
#define AB_E2  640
#define AB_A3  768
#define AB_E3  896

__device__ __forceinline__ void atomAddD(double* p, double v) {
    __hip_atomic_fetch_add(p, v, __ATOMIC_RELAXED, __HIP_MEMORY_SCOPE_AGENT);
}
__device__ __forceinline__ unsigned short f2bs(float f) {
    const unsigned b = __float_as_uint(f);
    return (unsigned short)((b + 0x7FFFu + ((b >> 16) & 1u)) >> 16);   // RNE
}
__device__ __forceinline__ float bs2f(unsigned short u) {
    return __uint_as_float(((unsigned)u) << 16);
}

// ---------------------------------------------------------------------------
__global__ void zero_stats_kernel(double* __restrict__ st) {
    for (int i = threadIdx.x; i < N_STATS; i += 256) st[i] = 0.0;
}

// W2/W3 f32 [d][c] -> bf16 [d][c]
__global__ __launch_bounds__(256) void castW_kernel(
    const float* __restrict__ W2, const float* __restrict__ W3,
    unsigned short* __restrict__ Wb2, unsigned short* __restrict__ Wb3)
{
    const int i = blockIdx.x * 256 + threadIdx.x;   // 0..16383
    Wb2[i] = f2bs(W2[i]);
    Wb3[i] = f2bs(W3[i]);
}

// ---------------------------------------------------------------------------
// kNN + grouped offsets + layer-1 moment partials (round-9 proven).
__global__ __launch_bounds__(1024) void knn_group_kernel(
    const float* __restrict__ x, float* __restrict__ g, float* __restrict__ kpart)
{
    __shared__ __align__(16) float4 xs4[N_];   // 32 KB {x,y,z,|x|^2}
    __shared__ float listD[16][CAP];           // 8 KB
    __shared__ int   listI[16][CAP];           // 8 KB
    __shared__ float spart[16][12];
    const int b   = blockIdx.y;
    const int tid = threadIdx.x;
    const int wv  = tid >> 6;
    const int ln  = tid & 63;
    const int n   = blockIdx.x * 16 + wv;
    const float* xb = x + (size_t)b * 3 * N_;

    for (int i = tid; i < N_; i += 1024) {
        const float a0 = xb[i], a1 = xb[N_ + i], a2 = xb[2*N_ + i];
        const float sq = __fadd_rn(__fadd_rn(__fmul_rn(a0,a0), __fmul_rn(a1,a1)), __fmul_rn(a2,a2));
        xs4[i] = make_float4(a0, a1, a2, sq);
    }
    __syncthreads();

    const float4 me = xs4[n];
    const float xn0 = me.x, xn1 = me.y, xn2 = me.z, sqn = me.w;

    // ---- Pass A
    float dreg[32];
    float lmin = INFINITY;
    #pragma unroll
    for (int i = 0; i < 32; ++i) {
        const float4 q = xs4[ln + 64*i];
        dreg[i] = __fadd_rn(__fmaf_rn(-2.f, __fmaf_rn(xn2, q.z, __fmaf_rn(xn1, q.y, __fmul_rn(xn0, q.x))), sqn), q.w);
        lmin = fminf(lmin, dreg[i]);
    }

    // ---- bound B' = max over 8 groups of (min over each 8-lane group)
    float gm = lmin;
    gm = fminf(gm, __shfl_xor(gm, 1));
    gm = fminf(gm, __shfl_xor(gm, 2));
    gm = fminf(gm, __shfl_xor(gm, 4));
    float Bb = gm;
    Bb = fmaxf(Bb, __shfl_xor(Bb, 8));
    Bb = fmaxf(Bb, __shfl_xor(Bb, 16));
    Bb = fmaxf(Bb, __shfl_xor(Bb, 32));

    // ---- Pass B: ballot-compact candidates with d <= B'
    unsigned base = 0;
    #pragma unroll
    for (int i = 0; i < 32; ++i) {
        const bool pred = (dreg[i] <= Bb);
        const unsigned long long mk = __ballot(pred);
        if (pred) {
            const unsigned pos = base + (unsigned)__popcll(mk & ((1ull << ln) - 1ull));
            if (pos < CAP) { listD[wv][pos] = dreg[i]; listI[wv][pos] = ln + 64*i; }
        }
        base += (unsigned)__popcll(mk);
    }
    const int cnt = (base < CAP) ? (int)base : CAP;

    // ---- Pass C: 8x wave lex-argmin over compacted list (exact top_k)
    float cd0 = (ln < cnt)      ? listD[wv][ln]      : INFINITY;
    int   ci0 = (ln < cnt)      ? listI[wv][ln]      : 0x7FFFFFFF;
    float cd1 = (ln + 64 < cnt) ? listD[wv][ln + 64] : INFINITY;
    int   ci1 = (ln + 64 < cnt) ? listI[wv][ln + 64] : 0x7FFFFFFF;
    int myi = 0;
    #pragma unroll
    for (int sel = 0; sel < 8; ++sel) {
        const bool sw = (cd1 < cd0) || (cd1 == cd0 && ci1 < ci0);
        float pd = sw ? cd1 : cd0;
        int   pi = sw ? ci1 : ci0;
        #pragma unroll
        for (int m = 1; m < 64; m <<= 1) {
            const float od = __shfl_xor(pd, m);
            const int   oi = __shfl_xor(pi, m);
            if ((od < pd) || (od == pd && oi < pi)) { pd = od; pi = oi; }
        }
        myi = (ln == sel) ? pi : myi;
        if (ci0 == pi) cd0 = INFINITY;
        if (ci1 == pi) cd1 = INFINITY;
    }

    // ---- gather, g-write, stats (lanes 0..7 hold the 8 neighbors)
    if (ln < 8) {
        const float4 q = xs4[myi];
        const float g0  = q.x - xn0;
        const float g1v = q.y - xn1;
        const float g2v = q.z - xn2;
        const size_t basep = ((size_t)b*N_ + n) * KNN;
        g[0*P_ + basep + ln] = g0;
        g[1*P_ + basep + ln] = g1v;
        g[2*P_ + basep + ln] = g2v;
        float s0 = g0, s1 = g1v, s2 = g2v;
        float s00 = g0*g0, s01 = g0*g1v, s02 = g0*g2v;
        float s11 = g1v*g1v, s12 = g1v*g2v, s22 = g2v*g2v;
        #pragma unroll
        for (int m = 1; m < 8; m <<= 1) {
            s0 += __shfl_xor(s0, m);  s1 += __shfl_xor(s1, m);  s2 += __shfl_xor(s2, m);
            s00 += __shfl_xor(s00, m); s01 += __shfl_xor(s01, m); s02 += __shfl_xor(s02, m);
            s11 += __shfl_xor(s11, m); s12 += __shfl_xor(s12, m); s22 += __shfl_xor(s22, m);
        }
        if (ln == 0) {
            spart[wv][0] = s0;  spart[wv][1] = s1;  spart[wv][2] = s2;
            spart[wv][3] = s00; spart[wv][4] = s01; spart[wv][5] = s02;
            spart[wv][6] = s11; spart[wv][7] = s12; spart[wv][8] = s22;
        }
    }
    __syncthreads();
    if (tid < 9) {
        float a = 0.f;
        #pragma unroll
        for (int w = 0; w < 16; ++w) a += spart[w][tid];
        kpart[tid*NKBLK + blockIdx.y*128 + blockIdx.x] = a;
    }
}

// ---------------------------------------------------------------------------
__global__ __launch_bounds__(128) void finalize1_kernel(
    const float* __restrict__ kpart, const float* __restrict__ W1,
    const float* __restrict__ b1, const float* __restrict__ g1,
    const float* __restrict__ be1, float* __restrict__ ab)
{
    __shared__ double red[128];
    __shared__ double S9[9];
    const int tid = threadIdx.x;
    for (int m = 0; m < 9; ++m) {
        double a = 0.0;
        for (int i = tid; i < NKBLK; i += 128) a += (double)kpart[m*NKBLK + i];
        red[tid] = a;
        __syncthreads();
        if (tid == 0) {
            double s = 0.0;
            for (int j = 0; j < 128; ++j) s += red[j];
            S9[m] = s;
        }
        __syncthreads();
    }
    const int d = tid;
    const double inv = 1.0 / (double)P_;
    const double mu0 = S9[0]*inv, mu1 = S9[1]*inv, mu2 = S9[2]*inv;
    const double c00 = S9[3]*inv - mu0*mu0;
    const double c01 = S9[4]*inv - mu0*mu1;
    const double c02 = S9[5]*inv - mu0*mu2;
    const double c11 = S9[6]*inv - mu1*mu1;
    const double c12 = S9[7]*inv - mu1*mu2;
    const double c22 = S9[8]*inv - mu2*mu2;
    const double w0 = W1[d*3+0], w1 = W1[d*3+1], w2 = W1[d*3+2];
    const double mean = w0*mu0 + w1*mu1 + w2*mu2 + (double)b1[d];
    double var = w0*w0*c00 + w1*w1*c11 + w2*w2*c22
               + 2.0*(w0*w1*c01 + w0*w2*c02 + w1*w2*c12);
    if (var < 0.0) var = 0.0;
    const double r = 1.0 / sqrt(var + 1e-5);
    const double alpha = (double)g1[d] * r;
    const double beta  = (double)be1[d] - mean*alpha;
    ab[AB_W1F + 4*d + 0] = (float)(alpha * w0);
    ab[AB_W1F + 4*d + 1] = (float)(alpha * w1);
    ab[AB_W1F + 4*d + 2] = (float)(alpha * w2);
    ab[AB_W1F + 4*d + 3] = (float)(alpha * (double)b1[d] + beta);
}

__global__ void finalize23_kernel(
    const double* __restrict__ st, int soff,
    const float* __restrict__ gg, const float* __restrict__ bee,
    float* __restrict__ ab, int aoff)
{
    const int d = threadIdx.x;
    if (d >= DIM) return;
    double s1 = 0.0, s2 = 0.0;
    #pragma unroll
    for (int k = 0; k < NBANK; ++k) {
        s1 += st[soff + k*256 + d];
        s2 += st[soff + k*256 + 128 + d];
    }
    const double inv = 1.0 / (double)P_;
    const double mean = s1 * inv;
    double var = s2 * inv - mean*mean;
    if (var < 0.0) var = 0.0;
    const double r = 1.0 / sqrt(var + 1e-5);
    const double alpha = (double)gg[d] * r;
    ab[aoff + d]       = (float)alpha;
    ab[aoff + 128 + d] = (float)((double)bee[d] - mean*alpha);
}

// ---------------------------------------------------------------------------
// MFMA conv: block = 128d x 128p, 4 waves; wave w owns d in [32w,32w+32).
// Ht[p][c] bf16 in LDS (stride 128, c-octet XOR(p&7) swizzle).
// A-frags preloaded from global bf16 W[d][c]. mfma_f32_16x16x32_bf16.
// SRC 0: H from g via folded W1f (conv2).
// SRC 1: H = relu(a2*y2t+e2), y2t p-major, coalesced b128 row loads (conv3).
// MODE 0: y2t (bf16, p-major) via LDS transpose (stride 136) + stats.
// MODE 3: stats + per-point max/min -> ymm.
template<int SRC, int MODE>
__global__ __launch_bounds__(256) void conv_kernel(
    const float* __restrict__ gsrc, const unsigned short* __restrict__ ybsrc,
    const unsigned short* __restrict__ Wb, const float* __restrict__ ab,
    const float* __restrict__ bias, unsigned short* __restrict__ ybdst,
    float* __restrict__ ymm, double* __restrict__ stats, int statoff)
{
    __shared__ __align__(16) short Hs[128*136];   // 34 KB (staging stride 128; transpose stride 136)
    const int tid = threadIdx.x;
    const int p0g = blockIdx.x * 128;
    const int w  = tid >> 6, ln = tid & 63;
    const int lg = ln >> 4, lr = ln & 15;

    bf16x8 afrag[2][4];
    #pragma unroll
    for (int dtl = 0; dtl < 2; ++dtl)
        #pragma unroll
        for (int ks = 0; ks < 4; ++ks)
            afrag[dtl][ks] = *(const bf16x8*)&Wb[(32*w + 16*dtl + lr)*DIM + (4*ks + lg)*8];

    if constexpr (SRC == 0) {
        const int sp = 64*(w & 1) + ln;     // 0..127
        const int ob = w >> 1;              // 0 or 1
        const float gx = gsrc[0*P_ + p0g + sp];
        const float gy = gsrc[1*P_ + p0g + sp];
        const float gz = gsrc[2*P_ + p0g + sp];
        #pragma unroll
        for (int it = 0; it < 8; ++it) {
            const int o = ob + 2*it;
            bf16x8 hv;
            #pragma unroll
            for (int j = 0; j < 8; ++j) {
                const int c = 8*o + j;
                const float4 wf = *(const float4*)&ab[AB_W1F + 4*c];
                const float h = fmaxf(__fmaf_rn(wf.x, gx, __fmaf_rn(wf.y, gy, __fmaf_rn(wf.z, gz, wf.w))), 0.f);
                hv[j] = (short)f2bs(h);
            }
            *(bf16x8*)&Hs[sp*128 + ((o ^ (sp & 7)) * 8)] = hv;
        }
    } else {
        // coalesced: wave-inst covers 4 rows x 256B = contiguous 1KB of y2t
        const int myoct = tid & 15;          // fixed c-octet per thread
        const float4 aLo = *(const float4*)&ab[AB_A2 + myoct*8];
        const float4 aHi = *(const float4*)&ab[AB_A2 + myoct*8 + 4];
        const float4 eLo = *(const float4*)&ab[AB_E2 + myoct*8];
        const float4 eHi = *(const float4*)&ab[AB_E2 + myoct*8 + 4];
        const float av[8] = {aLo.x,aLo.y,aLo.z,aLo.w,aHi.x,aHi.y,aHi.z,aHi.w};
        const float ev[8] = {eLo.x,eLo.y,eLo.z,eLo.w,eHi.x,eHi.y,eHi.z,eHi.w};
        #pragma unroll
        for (int it = 0; it < 8; ++it) {
            const int p = it*16 + (tid >> 4);
            const bf16x8 raw = *(const bf16x8*)&ybsrc[(size_t)(p0g + p)*128 + myoct*8];
            bf16x8 hv;
            #pragma unroll
            for (int j = 0; j < 8; ++j) {
                const float v = bs2f((unsigned short)raw[j]);
                hv[j] = (short)f2bs(fmaxf(__fmaf_rn(av[j], v, ev[j]), 0.f));
            }
            *(bf16x8*)&Hs[p*128 + ((myoct ^ (p & 7)) * 8)] = hv;
        }
    }
    __syncthreads();

    f32x4 acc[2][8];
    #pragma unroll
    for (int i = 0; i < 2; ++i)
        #pragma unroll
        for (int j = 0; j < 8; ++j)
            acc[i][j] = (f32x4){0.f, 0.f, 0.f, 0.f};

    #pragma unroll
    for (int ks = 0; ks < 4; ++ks) {
        #pragma unroll
        for (int pt = 0; pt < 8; ++pt) {
            const int p = 16*pt + lr;
            const bf16x8 bf = *(const bf16x8*)&Hs[p*128 + (((4*ks + lg) ^ (lr & 7)) * 8)];
            acc[0][pt] = __builtin_amdgcn_mfma_f32_16x16x32_bf16(afrag[0][ks], bf, acc[0][pt], 0, 0, 0);
            acc[1][pt] = __builtin_amdgcn_mfma_f32_16x16x32_bf16(afrag[1][ks], bf, acc[1][pt], 0, 0, 0);
        }
    }

    // ---- stats (both modes) + MODE 3 minmax
    const int bank = blockIdx.x & (NBANK-1);
    #pragma unroll
    for (int dtl = 0; dtl < 2; ++dtl) {
        #pragma unroll
        for (int r = 0; r < 4; ++r) {
            const int d = 32*w + 16*dtl + 4*lg + r;
            const float bb = bias[d];
            float v[8];
            #pragma unroll
            for (int pt = 0; pt < 8; ++pt) v[pt] = acc[dtl][pt][r] + bb;

            float s1 = ((v[0]+v[1])+(v[2]+v[3])) + ((v[4]+v[5])+(v[6]+v[7]));
            float s2 = ((v[0]*v[0]+v[1]*v[1])+(v[2]*v[2]+v[3]*v[3]))
                     + ((v[4]*v[4]+v[5]*v[5])+(v[6]*v[6]+v[7]*v[7]));
            #pragma unroll
            for (int m = 1; m < 16; m <<= 1) { s1 += __shfl_xor(s1, m); s2 += __shfl_xor(s2, m); }
            if (lr == 0) {
                atomAddD(&stats[statoff + bank*256 + d], (double)s1);
                atomAddD(&stats[statoff + bank*256 + 128 + d], (double)s2);
            }

            if constexpr (MODE == 3) {
                #pragma unroll
                for (int pt = 0; pt < 8; ++pt) {
                    float mx = v[pt], mn = v[pt];
                    float o1 = __shfl_xor(mx, 1); float o1n = __shfl_xor(mn, 1);
                    mx = fmaxf(mx, o1); mn = fminf(mn, o1n);
                    float o2x = __shfl_xor(mx, 2), o2n = __shfl_xor(mn, 2);
                    mx = fmaxf(mx, o2x); mn = fminf(mn, o2n);
                    float o4x = __shfl_xor(mx, 4), o4n = __shfl_xor(mn, 4);
                    mx = fmaxf(mx, o4x); mn = fminf(mn, o4n);
                    if ((lr & 7) == 0) {
                        const int slot = 2*pt + (lr >> 3);
                        float* yb = ymm + ((size_t)d*NBLK + blockIdx.x)*32;
                        yb[slot]      = mx;
                        yb[16 + slot] = mn;
                    }
                }
            }
        }
    }

    if constexpr (MODE == 0) {
        // ---- LDS transpose -> fully coalesced p-major stores
        __syncthreads();   // all waves done reading Hs (B-frags)
        #pragma unroll
        for (int dtl = 0; dtl < 2; ++dtl) {
            const int d0 = 32*w + 16*dtl + 4*lg;
            const float4 b4 = *(const float4*)&bias[d0];
            #pragma unroll
            for (int pt = 0; pt < 8; ++pt) {
                const int p = 16*pt + lr;
                bf16x4 pk;
                pk[0] = (short)f2bs(acc[dtl][pt][0] + b4.x);
                pk[1] = (short)f2bs(acc[dtl][pt][1] + b4.y);
                pk[2] = (short)f2bs(acc[dtl][pt][2] + b4.z);
                pk[3] = (short)f2bs(acc[dtl][pt][3] + b4.w);
                *(bf16x4*)&Hs[p*136 + d0] = pk;   // conflict-free (68-word rows)
            }
        }
        __syncthreads();
        #pragma unroll
        for (int it = 0; it < 8; ++it) {
            const int f = it*256 + tid;
            const int row = f >> 4, ch = f & 15;
            const bf16x8 vv = *(const bf16x8*)&Hs[row*136 + ch*8];
            *(bf16x8*)&ybdst[(size_t)(p0g + row)*128 + ch*8] = vv;   // contiguous 1KB/wave
        }
    }
}

// ---------------------------------------------------------------------------
// Epilogue: out[b,d,n] = relu(a3*(a3>=0 ? max_k : min_k) + e3)
__global__ __launch_bounds__(256) void bn3max_kernel(
    const float* __restrict__ ymm, const float* __restrict__ ab, float* __restrict__ out)
{
    const int idx = blockIdx.x*256 + threadIdx.x;   // over B*DIM*N
    const int n = idx & (N_-1);
    const int d = (idx >> 11) & (DIM-1);
    const int b = idx >> 18;
    const int pt  = b*N_ + n;
    const int blk = pt >> 4;
    const int j   = pt & 15;
    const size_t base = ((size_t)d*NBLK + blk) * 32;
    const float a = ab[AB_A3 + d], e = ab[AB_E3 + d];
    const float mx = ymm[base + j];
    const float mn = ymm[base + 16 + j];
    const float v = (a >= 0.f) ? mx : mn;
    out[idx] = fmaxf(__fmaf_rn(a, v, e), 0.f);
}

// ---------------------------------------------------------------------------
extern "C" void kernel_launch(void* const* d_in, const int* in_sizes, int n_in,
                              void* d_out, int out_size, void* d_ws, size_t ws_size,
                              hipStream_t stream) {
    (void)in_sizes; (void)n_in; (void)out_size; (void)ws_size;
    const float* x   = (const float*)d_in[0];
    const float* W1  = (const float*)d_in[1];
    const float* b1  = (const float*)d_in[2];
    const float* g1  = (const float*)d_in[3];
    const float* be1 = (const float*)d_in[4];
    const float* W2  = (const float*)d_in[5];
    const float* b2  = (const float*)d_in[6];
    const float* g2  = (const float*)d_in[7];
    const float* be2 = (const float*)d_in[8];
    const float* W3  = (const float*)d_in[9];
    const float* b3  = (const float*)d_in[10];
    const float* g3  = (const float*)d_in[11];
    const float* be3 = (const float*)d_in[12];

    float*  out = (float*)d_out;
    char*   ws  = (char*)d_ws;
    float*          g   = (float*)(ws + OFF_G);
    unsigned short* y2t = (unsigned short*)(ws + OFF_Y2B);
    unsigned short* wb2 = (unsigned short*)(ws + OFF_WB2);
    unsigned short* wb3 = (unsigned short*)(ws + OFF_WB3);
    double*         st  = (double*)(ws + OFF_STATS);
    float*          ab  = (float*)(ws + OFF_AB);
    float*          kp  = (float*)(ws + OFF_KPART);
    float*          ymm = (float*)(ws + OFF_YMM);

    zero_stats_kernel<<<1, 256, 0, stream>>>(st);
    castW_kernel<<<64, 256, 0, stream>>>(W2, W3, wb2, wb3);
    knn_group_kernel<<<dim3(128, B_), 1024, 0, stream>>>(x, g, kp);
    finalize1_kernel<<<1, 128, 0, stream>>>(kp, W1, b1, g1, be1, ab);
    conv_kernel<0,0><<<NBLK, 256, 0, stream>>>(g, nullptr, wb2, ab, b2, y2t, nullptr, st, I_S2);
    finalize23_kernel<<<1, 128, 0, stream>>>(st, I_S2, g2, be2, ab, AB_A2);
    conv_kernel<1,3><<<NBLK, 256, 0, stream>>>(nullptr, y2t, wb3, ab, b3, nullptr, ymm, st, I_S3);
    finalize23_kernel<<<1, 128, 0, stream>>>(st, I_S3, g3, be3, ab, AB_A3);
    bn3max_kernel<<<(B_*DIM*N_)/256, 256, 0, stream>>>(ymm, ab, out);
}

// Round 11
// 193.747 us; speedup vs baseline: 1.6346x; 1.3013x over previous
//
#include <hip/hip_runtime.h>
#include <hip/hip_bf16.h>
#include <math.h>

// ---------------------------------------------------------------------------
// FeatureNet (DGCNN edge-conv block), MI355X / gfx950, round 11.
//
// Round-11 changes:
//  * kNN Pass C: packed-u64-key 64-lane bitonic sort (42 hw shuffles vs 96),
//    wave-uniform fallback to 8x argmin when cnt>64. Pass B writes b64 keys.
//  * Conv stats/minmax reductions via DPP (VALU pipe) instead of ds_swizzle.
//  * castW folded into conv A-frag load; zero_stats folded into knn(0,0);
//    finalize1 wave-parallel. 9 -> 7 kernel launches.
// ---------------------------------------------------------------------------

#define B_   16
#define N_   2048
#define KNN  8
#define DIM  128
#define P_   (B_*N_*KNN)   // 262144
#define CAP  128
#define NBLK 2048          // conv blocks (128 p each)

typedef __attribute__((ext_vector_type(8))) short bf16x8;
typedef __attribute__((ext_vector_type(4))) short bf16x4;
typedef __attribute__((ext_vector_type(4))) float f32x4;

// ws layout (bytes)
#define OFF_G     0ull
#define SZ_G      ((size_t)3*P_*4)             // 3,145,728
#define OFF_Y2B   (OFF_G + SZ_G)
#define SZ_Y2B    ((size_t)DIM*P_*2)           // 67,108,864  (y2t[p][c])
#define OFF_STATS (OFF_Y2B + SZ_Y2B)
#define N_STATS   4112
#define SZ_STATS  ((size_t)N_STATS*8)
#define OFF_AB    (OFF_STATS + SZ_STATS)
#define SZ_AB     4096ull
#define OFF_KPART (OFF_AB + SZ_AB)
#define NKBLK     2048
#define SZ_KPART  ((size_t)9*NKBLK*4)
#define OFF_YMM   (OFF_KPART + SZ_KPART)
#define SZ_YMM    ((size_t)DIM*NBLK*32*4)      // 33,554,432

// stats (f64) indices
#define I_S2   16
#define I_S3   (16 + 8*256)
#define NBANK  8

// ab (float) layout
#define AB_W1F 0
#define AB_A2  512
#define AB_E2  640
#define AB_A3  768
#define AB_E3  896

// DPP ctrl codes (all source lanes valid -> no bound_ctrl concerns)
#define DPP_XOR1   0xB1    // quad_perm [1,0,3,2]
#define DPP_XOR2   0x4E    // quad_perm [2,3,0,1]
#define DPP_HALFM  0x141   // row_half_mirror: lane ^ 7 (other quad within 8)
#define DPP_MIRROR 0x140   // row_mirror: lane ^ 15 (other 8 within 16)

template<int C>
__device__ __forceinline__ float dppf(float v) {
    return __int_as_float(__builtin_amdgcn_update_dpp(
        __float_as_int(v), __float_as_int(v), C, 0xF, 0xF, false));
}

__device__ __forceinline__ void atomAddD(double* p, double v) {
    __hip_atomic_fetch_add(p, v, __ATOMIC_RELAXED, __HIP_MEMORY_SCOPE_AGENT);
}
__device__ __forceinline__ unsigned short f2bs(float f) {
    const unsigned b = __float_as_uint(f);
    return (unsigned short)((b + 0x7FFFu + ((b >> 16) & 1u)) >> 16);   // RNE
}
__device__ __forceinline__ float bs2f(unsigned short u) {
    return __uint_as_float(((unsigned)u) << 16);
}

// ---------------------------------------------------------------------------
// kNN + grouped offsets + layer-1 moment partials + stats zeroing (block 0,0).
// Block = 1024 threads = 16 waves = 16 points; wave = one point.
// Distance arithmetic bit-identical to passing rounds 1-10.
__global__ __launch_bounds__(1024) void knn_group_kernel(
    const float* __restrict__ x, float* __restrict__ g,
    float* __restrict__ kpart, double* __restrict__ st)
{
    __shared__ __align__(16) float4 xs4[N_];           // 32 KB {x,y,z,|x|^2}
    __shared__ unsigned long long listK[16][CAP];      // 16 KB packed keys
    __shared__ float spart[16][12];
    const int b   = blockIdx.y;
    const int tid = threadIdx.x;
    const int wv  = tid >> 6;
    const int ln  = tid & 63;
    const int n   = blockIdx.x * 16 + wv;
    const float* xb = x + (size_t)b * 3 * N_;

    if (blockIdx.x == 0 && blockIdx.y == 0)
        for (int i = tid; i < N_STATS; i += 1024) st[i] = 0.0;

    for (int i = tid; i < N_; i += 1024) {
        const float a0 = xb[i], a1 = xb[N_ + i], a2 = xb[2*N_ + i];
        const float sq = __fadd_rn(__fadd_rn(__fmul_rn(a0,a0), __fmul_rn(a1,a1)), __fmul_rn(a2,a2));
        xs4[i] = make_float4(a0, a1, a2, sq);
    }
    __syncthreads();

    const float4 me = xs4[n];
    const float xn0 = me.x, xn1 = me.y, xn2 = me.z, sqn = me.w;

    // ---- Pass A: distances in registers + lane min
    float dreg[32];
    float lmin = INFINITY;
    #pragma unroll
    for (int i = 0; i < 32; ++i) {
        const float4 q = xs4[ln + 64*i];
        dreg[i] = __fadd_rn(__fmaf_rn(-2.f, __fmaf_rn(xn2, q.z, __fmaf_rn(xn1, q.y, __fmul_rn(xn0, q.x))), sqn), q.w);
        lmin = fminf(lmin, dreg[i]);
    }

    // ---- bound B' = max over 8 groups of (min over each 8-lane group)
    float gm = lmin;
    gm = fminf(gm, __shfl_xor(gm, 1));
    gm = fminf(gm, __shfl_xor(gm, 2));
    gm = fminf(gm, __shfl_xor(gm, 4));
    float Bb = gm;
    Bb = fmaxf(Bb, __shfl_xor(Bb, 8));
    Bb = fmaxf(Bb, __shfl_xor(Bb, 16));
    Bb = fmaxf(Bb, __shfl_xor(Bb, 32));

    // ---- Pass B: ballot-compact packed keys (orderable(d)<<32 | idx)
    unsigned base = 0;
    #pragma unroll
    for (int i = 0; i < 32; ++i) {
        const bool pred = (dreg[i] <= Bb);
        const unsigned long long mk = __ballot(pred);
        if (pred) {
            const unsigned pos = base + (unsigned)__popcll(mk & ((1ull << ln) - 1ull));
            if (pos < CAP) {
                const unsigned u = __float_as_uint(dreg[i]);
                const unsigned od = u ^ ((unsigned)(((int)u) >> 31) | 0x80000000u);
                listK[wv][pos] = (((unsigned long long)od) << 32) | (unsigned)(ln + 64*i);
            }
        }
        base += (unsigned)__popcll(mk);
    }
    const int cnt = (base < CAP) ? (int)base : CAP;

    // ---- Pass C: exact top-8 selection (lex (d,idx) == lax.top_k order)
    int myi = 0;
    if (cnt <= 64) {
        // 64-lane bitonic sort of packed keys; lanes 0..7 = ranks 0..7
        unsigned long long K = (ln < cnt) ? listK[wv][ln] : ~0ull;
        #pragma unroll
        for (int k = 2; k <= 64; k <<= 1) {
            #pragma unroll
            for (int j = k >> 1; j >= 1; j >>= 1) {
                const unsigned long long o = __shfl_xor(K, j);
                const bool takeMin = (((ln & j) == 0) == ((ln & k) == 0));
                const bool oLess = (o < K);
                if (takeMin ? oLess : !oLess) K = o;
            }
        }
        myi = (int)(unsigned)K;
    } else {
        // rare fallback: 8x wave argmin over both slots
        unsigned long long K0 = (ln < cnt)      ? listK[wv][ln]      : ~0ull;
        unsigned long long K1 = (ln + 64 < cnt) ? listK[wv][ln + 64] : ~0ull;
        #pragma unroll
        for (int sel = 0; sel < 8; ++sel) {
            unsigned long long p = (K1 < K0) ? K1 : K0;
            #pragma unroll
            for (int m = 1; m < 64; m <<= 1) {
                const unsigned long long o = __shfl_xor(p, m);
                if (o < p) p = o;
            }
            if (ln == sel) myi = (int)(unsigned)p;
            if (K0 == p) K0 = ~0ull;
            if (K1 == p) K1 = ~0ull;
        }
    }

    // ---- gather, g-write, stats (lanes 0..7 hold the 8 neighbors)
    if (ln < 8) {
        const float4 q = xs4[myi];
        const float g0  = q.x - xn0;
        const float g1v = q.y - xn1;
        const float g2v = q.z - xn2;
        const size_t basep = ((size_t)b*N_ + n) * KNN;
        g[0*P_ + basep + ln] = g0;
        g[1*P_ + basep + ln] = g1v;
        g[2*P_ + basep + ln] = g2v;
        float s0 = g0, s1 = g1v, s2 = g2v;
        float s00 = g0*g0, s01 = g0*g1v, s02 = g0*g2v;
        float s11 = g1v*g1v, s12 = g1v*g2v, s22 = g2v*g2v;
        #pragma unroll
        for (int m = 1; m < 8; m <<= 1) {
            s0 += __shfl_xor(s0, m);  s1 += __shfl_xor(s1, m);  s2 += __shfl_xor(s2, m);
            s00 += __shfl_xor(s00, m); s01 += __shfl_xor(s01, m); s02 += __shfl_xor(s02, m);
            s11 += __shfl_xor(s11, m); s12 += __shfl_xor(s12, m); s22 += __shfl_xor(s22, m);
        }
        if (ln == 0) {
            spart[wv][0] = s0;  spart[wv][1] = s1;  spart[wv][2] = s2;
            spart[wv][3] = s00; spart[wv][4] = s01; spart[wv][5] = s02;
            spart[wv][6] = s11; spart[wv][7] = s12; spart[wv][8] = s22;
        }
    }
    __syncthreads();
    if (tid < 9) {
        float a = 0.f;
        #pragma unroll
        for (int w = 0; w < 16; ++w) a += spart[w][tid];
        kpart[tid*NKBLK + blockIdx.y*128 + blockIdx.x] = a;
    }
}

// ---------------------------------------------------------------------------
// Layer-1 BN stats from g moment partials (wave-parallel reduce); emit W1f.
__global__ __launch_bounds__(1024) void finalize1_kernel(
    const float* __restrict__ kpart, const float* __restrict__ W1,
    const float* __restrict__ b1, const float* __restrict__ g1,
    const float* __restrict__ be1, float* __restrict__ ab)
{
    __shared__ double S9[9];
    const int tid = threadIdx.x;
    const int w = tid >> 6, l = tid & 63;
    if (w < 9) {
        double a = 0.0;
        #pragma unroll
        for (int i = 0; i < 32; ++i) a += (double)kpart[w*NKBLK + l + 64*i];
        #pragma unroll
        for (int m = 1; m < 64; m <<= 1) a += __shfl_xor(a, m);
        if (l == 0) S9[w] = a;
    }
    __syncthreads();
    if (tid < 128) {
        const int d = tid;
        const double inv = 1.0 / (double)P_;
        const double mu0 = S9[0]*inv, mu1 = S9[1]*inv, mu2 = S9[2]*inv;
        const double c00 = S9[3]*inv - mu0*mu0;
        const double c01 = S9[4]*inv - mu0*mu1;
        const double c02 = S9[5]*inv - mu0*mu2;
        const double c11 = S9[6]*inv - mu1*mu1;
        const double c12 = S9[7]*inv - mu1*mu2;
        const double c22 = S9[8]*inv - mu2*mu2;
        const double w0 = W1[d*3+0], w1 = W1[d*3+1], w2 = W1[d*3+2];
        const double mean = w0*mu0 + w1*mu1 + w2*mu2 + (double)b1[d];
        double var = w0*w0*c00 + w1*w1*c11 + w2*w2*c22
                   + 2.0*(w0*w1*c01 + w0*w2*c02 + w1*w2*c12);
        if (var < 0.0) var = 0.0;
        const double r = 1.0 / sqrt(var + 1e-5);
        const double alpha = (double)g1[d] * r;
        const double beta  = (double)be1[d] - mean*alpha;
        ab[AB_W1F + 4*d + 0] = (float)(alpha * w0);
        ab[AB_W1F + 4*d + 1] = (float)(alpha * w1);
        ab[AB_W1F + 4*d + 2] = (float)(alpha * w2);
        ab[AB_W1F + 4*d + 3] = (float)(alpha * (double)b1[d] + beta);
    }
}

__global__ void finalize23_kernel(
    const double* __restrict__ st, int soff,
    const float* __restrict__ gg, const float* __restrict__ bee,
    float* __restrict__ ab, int aoff)
{
    const int d = threadIdx.x;
    if (d >= DIM) return;
    double s1 = 0.0, s2 = 0.0;
    #pragma unroll
    for (int k = 0; k < NBANK; ++k) {
        s1 += st[soff + k*256 + d];
        s2 += st[soff + k*256 + 128 + d];
    }
    const double inv = 1.0 / (double)P_;
    const double mean = s1 * inv;
    double var = s2 * inv - mean*mean;
    if (var < 0.0) var = 0.0;
    const double r = 1.0 / sqrt(var + 1e-5);
    const double alpha = (double)gg[d] * r;
    ab[aoff + d]       = (float)alpha;
    ab[aoff + 128 + d] = (float)((double)bee[d] - mean*alpha);
}

// ---------------------------------------------------------------------------
// MFMA conv: block = 128d x 128p, 4 waves; wave w owns d in [32w,32w+32).
// Ht[p][c] bf16 in LDS (stride 128, c-octet XOR(p&7) swizzle).
// A-frags loaded from f32 W[d][c] + in-reg bf16 cast (castW kernel removed).
// Stats & minmax reductions via DPP (VALU) instead of ds_swizzle (LDS pipe).
// SRC 0: H from g via folded W1f (conv2).
// SRC 1: H = relu(a2*y2t+e2), y2t p-major, coalesced b128 row loads (conv3).
// MODE 0: y2t (bf16, p-major) via LDS transpose (stride 136) + stats.
// MODE 3: stats + per-point max/min -> ymm.
template<int SRC, int MODE>
__global__ __launch_bounds__(256) void conv_kernel(
    const float* __restrict__ gsrc, const unsigned short* __restrict__ ybsrc,
    const float* __restrict__ Wf, const float* __restrict__ ab,
    const float* __restrict__ bias, unsigned short* __restrict__ ybdst,
    float* __restrict__ ymm, double* __restrict__ stats, int statoff)
{
    __shared__ __align__(16) short Hs[128*136];   // staging stride 128; transpose stride 136
    const int tid = threadIdx.x;
    const int p0g = blockIdx.x * 128;
    const int w  = tid >> 6, ln = tid & 63;
    const int lg = ln >> 4, lr = ln & 15;

    bf16x8 afrag[2][4];
    #pragma unroll
    for (int dtl = 0; dtl < 2; ++dtl)
        #pragma unroll
        for (int ks = 0; ks < 4; ++ks) {
            const float* wr = &Wf[(size_t)(32*w + 16*dtl + lr)*DIM + (4*ks + lg)*8];
            const float4 a4 = *(const float4*)wr;
            const float4 b4 = *(const float4*)(wr + 4);
            bf16x8 f;
            f[0]=(short)f2bs(a4.x); f[1]=(short)f2bs(a4.y); f[2]=(short)f2bs(a4.z); f[3]=(short)f2bs(a4.w);
            f[4]=(short)f2bs(b4.x); f[5]=(short)f2bs(b4.y); f[6]=(short)f2bs(b4.z); f[7]=(short)f2bs(b4.w);
            afrag[dtl][ks] = f;
        }

    if constexpr (SRC == 0) {
        const int sp = 64*(w & 1) + ln;     // 0..127
        const int ob = w >> 1;              // 0 or 1
        const float gx = gsrc[0*P_ + p0g + sp];
        const float gy = gsrc[1*P_ + p0g + sp];
        const float gz = gsrc[2*P_ + p0g + sp];
        #pragma unroll
        for (int it = 0; it < 8; ++it) {
            const int o = ob + 2*it;
            bf16x8 hv;
            #pragma unroll
            for (int j = 0; j < 8; ++j) {
                const int c = 8*o + j;
                const float4 wf = *(const float4*)&ab[AB_W1F + 4*c];
                const float h = fmaxf(__fmaf_rn(wf.x, gx, __fmaf_rn(wf.y, gy, __fmaf_rn(wf.z, gz, wf.w))), 0.f);
                hv[j] = (short)f2bs(h);
            }
            *(bf16x8*)&Hs[sp*128 + ((o ^ (sp & 7)) * 8)] = hv;
        }
    } else {
        const int myoct = tid & 15;          // fixed c-octet per thread
        const float4 aLo = *(const float4*)&ab[AB_A2 + myoct*8];
        const float4 aHi = *(const float4*)&ab[AB_A2 + myoct*8 + 4];
        const float4 eLo = *(const float4*)&ab[AB_E2 + myoct*8];
        const float4 eHi = *(const float4*)&ab[AB_E2 + myoct*8 + 4];
        const float av[8] = {aLo.x,aLo.y,aLo.z,aLo.w,aHi.x,aHi.y,aHi.z,aHi.w};
        const float ev[8] = {eLo.x,eLo.y,eLo.z,eLo.w,eHi.x,eHi.y,eHi.z,eHi.w};
        #pragma unroll
        for (int it = 0; it < 8; ++it) {
            const int p = it*16 + (tid >> 4);
            const bf16x8 raw = *(const bf16x8*)&ybsrc[(size_t)(p0g + p)*128 + myoct*8];
            bf16x8 hv;
            #pragma unroll
            for (int j = 0; j < 8; ++j) {
                const float v = bs2f((unsigned short)raw[j]);
                hv[j] = (short)f2bs(fmaxf(__fmaf_rn(av[j], v, ev[j]), 0.f));
            }
            *(bf16x8*)&Hs[p*128 + ((myoct ^ (p & 7)) * 8)] = hv;
        }
    }
    __syncthreads();

    f32x4 acc[2][8];
    #pragma unroll
    for (int i = 0; i < 2; ++i)
        #pragma unroll
        for (int j = 0; j < 8; ++j)
            acc[i][j] = (f32x4){0.f, 0.f, 0.f, 0.f};

    #pragma unroll
    for (int ks = 0; ks < 4; ++ks) {
        #pragma unroll
        for (int pt = 0; pt < 8; ++pt) {
            const int p = 16*pt + lr;
            const bf16x8 bf = *(const bf16x8*)&Hs[p*128 + (((4*ks + lg) ^ (lr & 7)) * 8)];
            acc[0][pt] = __builtin_amdgcn_mfma_f32_16x16x32_bf16(afrag[0][ks], bf, acc[0][pt], 0, 0, 0);
            acc[1][pt] = __builtin_amdgcn_mfma_f32_16x16x32_bf16(afrag[1][ks], bf, acc[1][pt], 0, 0, 0);
        }
    }

    // ---- stats (both modes) + MODE 3 minmax, all reductions on DPP/VALU
    const int bank = blockIdx.x & (NBANK-1);
    #pragma unroll
    for (int dtl = 0; dtl < 2; ++dtl) {
        #pragma unroll
        for (int r = 0; r < 4; ++r) {
            const int d = 32*w + 16*dtl + 4*lg + r;
            const float bb = bias[d];
            float v[8];
            #pragma unroll
            for (int pt = 0; pt < 8; ++pt) v[pt] = acc[dtl][pt][r] + bb;

            float s1 = ((v[0]+v[1])+(v[2]+v[3])) + ((v[4]+v[5])+(v[6]+v[7]));
            float s2 = ((v[0]*v[0]+v[1]*v[1])+(v[2]*v[2]+v[3]*v[3]))
                     + ((v[4]*v[4]+v[5]*v[5])+(v[6]*v[6]+v[7]*v[7]));
            s1 += dppf<DPP_XOR1>(s1);  s2 += dppf<DPP_XOR1>(s2);
            s1 += dppf<DPP_XOR2>(s1);  s2 += dppf<DPP_XOR2>(s2);
            s1 += dppf<DPP_HALFM>(s1); s2 += dppf<DPP_HALFM>(s2);
            s1 += dppf<DPP_MIRROR>(s1); s2 += dppf<DPP_MIRROR>(s2);
            if (lr == 0) {
                atomAddD(&stats[statoff + bank*256 + d], (double)s1);
                atomAddD(&stats[statoff + bank*256 + 128 + d], (double)s2);
            }

            if constexpr (MODE == 3) {
                #pragma unroll
                for (int pt = 0; pt < 8; ++pt) {
                    float mx = v[pt], mn = v[pt];
                    mx = fmaxf(mx, dppf<DPP_XOR1>(mx));  mn = fminf(mn, dppf<DPP_XOR1>(mn));
                    mx = fmaxf(mx, dppf<DPP_XOR2>(mx));  mn = fminf(mn, dppf<DPP_XOR2>(mn));
                    mx = fmaxf(mx, dppf<DPP_HALFM>(mx)); mn = fminf(mn, dppf<DPP_HALFM>(mn));
                    if ((lr & 7) == 0) {
                        const int slot = 2*pt + (lr >> 3);
                        float* yb = ymm + ((size_t)d*NBLK + blockIdx.x)*32;
                        yb[slot]      = mx;
                        yb[16 + slot] = mn;
                    }
                }
            }
        }
    }

    if constexpr (MODE == 0) {
        // ---- LDS transpose -> fully coalesced p-major stores
        __syncthreads();   // all waves done reading Hs (B-frags)
        #pragma unroll
        for (int dtl = 0; dtl < 2; ++dtl) {
            const int d0 = 32*w + 16*dtl + 4*lg;
            const float4 b4 = *(const float4*)&bias[d0];
            #pragma unroll
            for (int pt = 0; pt < 8; ++pt) {
                const int p = 16*pt + lr;
                bf16x4 pk;
                pk[0] = (short)f2bs(acc[dtl][pt][0] + b4.x);
                pk[1] = (short)f2bs(acc[dtl][pt][1] + b4.y);
                pk[2] = (short)f2bs(acc[dtl][pt][2] + b4.z);
                pk[3] = (short)f2bs(acc[dtl][pt][3] + b4.w);
                *(bf16x4*)&Hs[p*136 + d0] = pk;
            }
        }
        __syncthreads();
        #pragma unroll
        for (int it = 0; it < 8; ++it) {
            const int f = it*256 + tid;
            const int row = f >> 4, ch = f & 15;
            const bf16x8 vv = *(const bf16x8*)&Hs[row*136 + ch*8];
            *(bf16x8*)&ybdst[(size_t)(p0g + row)*128 + ch*8] = vv;
        }
    }
}

// ---------------------------------------------------------------------------
// Epilogue: out[b,d,n] = relu(a3*(a3>=0 ? max_k : min_k) + e3)
__global__ __launch_bounds__(256) void bn3max_kernel(
    const float* __restrict__ ymm, const float* __restrict__ ab, float* __restrict__ out)
{
    const int idx = blockIdx.x*256 + threadIdx.x;   // over B*DIM*N
    const int n = idx & (N_-1);
    const int d = (idx >> 11) & (DIM-1);
    const int b = idx >> 18;
    const int pt  = b*N_ + n;
    const int blk = pt >> 4;
    const int j   = pt & 15;
    const size_t base = ((size_t)d*NBLK + blk) * 32;
    const float a = ab[AB_A3 + d], e = ab[AB_E3 + d];
    const float mx = ymm[base + j];
    const float mn = ymm[base + 16 + j];
    const float v = (a >= 0.f) ? mx : mn;
    out[idx] = fmaxf(__fmaf_rn(a, v, e), 0.f);
}

// ---------------------------------------------------------------------------
extern "C" void kernel_launch(void* const* d_in, const int* in_sizes, int n_in,
                              void* d_out, int out_size, void* d_ws, size_t ws_size,
                              hipStream_t stream) {
    (void)in_sizes; (void)n_in; (void)out_size; (void)ws_size;
    const float* x   = (const float*)d_in[0];
    const float* W1  = (const float*)d_in[1];
    const float* b1  = (const float*)d_in[2];
    const float* g1  = (const float*)d_in[3];
    const float* be1 = (const float*)d_in[4];
    const float* W2  = (const float*)d_in[5];
    const float* b2  = (const float*)d_in[6];
    const float* g2  = (const float*)d_in[7];
    const float* be2 = (const float*)d_in[8];
    const float* W3  = (const float*)d_in[9];
    const float* b3  = (const float*)d_in[10];
    const float* g3  = (const float*)d_in[11];
    const float* be3 = (const float*)d_in[12];

    float*  out = (float*)d_out;
    char*   ws  = (char*)d_ws;
    float*          g   = (float*)(ws + OFF_G);
    unsigned short* y2t = (unsigned short*)(ws + OFF_Y2B);
    double*         st  = (double*)(ws + OFF_STATS);
    float*          ab  = (float*)(ws + OFF_AB);
    float*          kp  = (float*)(ws + OFF_KPART);
    float*          ymm = (float*)(ws + OFF_YMM);

    knn_group_kernel<<<dim3(128, B_), 1024, 0, stream>>>(x, g, kp, st);
    finalize1_kernel<<<1, 1024, 0, stream>>>(kp, W1, b1, g1, be1, ab);
    conv_kernel<0,0><<<NBLK, 256, 0, stream>>>(g, nullptr, W2, ab, b2, y2t, nullptr, st, I_S2);
    finalize23_kernel<<<1, 128, 0, stream>>>(st, I_S2, g2, be2, ab, AB_A2);
    conv_kernel<1,3><<<NBLK, 256, 0, stream>>>(nullptr, y2t, W3, ab, b3, nullptr, ymm, st, I_S3);
    finalize23_kernel<<<1, 128, 0, stream>>>(st, I_S3, g3, be3, ab, AB_A3);
    bn3max_kernel<<<(B_*DIM*N_)/256, 256, 0, stream>>>(ymm, ab, out);
}